// Round 1
// baseline (1682.910 us; speedup 1.0000x reference)
//
#include <hip/hip_runtime.h>
#include <math.h>

#define N_NODES 100000
#define N_EDGES 3200000
#define NBLK_SCAN 98   // ceil(100000/1024)

// ---------------- workspace layout ----------------
constexpr size_t al512(size_t x){ return (x + 511) & ~size_t(511); }
constexpr size_t o_wp   = 0;                                          // int[N]  write-ptrs / histogram
constexpr size_t o_off  = al512(o_wp   + (size_t)N_NODES*4);          // int[N+1] CSR offsets
constexpr size_t o_bs   = al512(o_off  + ((size_t)N_NODES+1)*4);      // int[128] scan block sums
constexpr size_t o_srcp = al512(o_bs   + 128*4);                      // int[E] src permuted by dst
constexpr size_t o_eidp = al512(o_srcp + (size_t)N_EDGES*4);          // int[E] edge id permuted
constexpr size_t o_U1   = al512(o_eidp + (size_t)N_EDGES*4);          // f[N*16]
constexpr size_t o_U2   = al512(o_U1   + (size_t)N_NODES*16*4);       // f[N*64]
constexpr size_t o_U3   = al512(o_U2   + (size_t)N_NODES*64*4);       // f[N*64]
constexpr size_t o_gs   = al512(o_U3   + (size_t)N_NODES*64*4);       // f[N] gate sums
constexpr size_t o_h1   = al512(o_gs   + (size_t)N_NODES*4);          // f[N*16]
constexpr size_t o_m1   = al512(o_h1   + (size_t)N_NODES*16*4);       // f[N*16]
constexpr size_t o_h2   = al512(o_m1   + (size_t)N_NODES*16*4);       // f[N*64]
constexpr size_t o_m2   = al512(o_h2   + (size_t)N_NODES*64*4);       // f[N*64]
constexpr size_t o_h3   = o_U2;   // U2 is dead after kdense1 -> reuse for h3
constexpr size_t o_m3   = o_m2;   // m2 is dead after kdense2 -> reuse for m3

#define BN_RSQRT 0.9999950000374997f   // 1/sqrt(1+1e-5)

// ---------------- CSR build ----------------
__global__ void khist(const int* __restrict__ dst, int* __restrict__ wp){
    int i = blockIdx.x*256 + threadIdx.x;
    if(i < N_EDGES) atomicAdd(&wp[dst[i]], 1);
}

__global__ void kscanA(const int* __restrict__ cnt, int* __restrict__ bs){
    __shared__ int s[256];
    int t = threadIdx.x;
    int base = blockIdx.x*1024 + t*4;
    int v = 0;
    #pragma unroll
    for(int k=0;k<4;k++){ int i = base+k; if(i < N_NODES) v += cnt[i]; }
    s[t] = v; __syncthreads();
    for(int off=128; off>0; off>>=1){ if(t<off) s[t] += s[t+off]; __syncthreads(); }
    if(t==0) bs[blockIdx.x] = s[0];
}

__global__ void kscanB(int* __restrict__ bs){
    __shared__ int s[128];
    int t = threadIdx.x;
    int v = (t < NBLK_SCAN) ? bs[t] : 0;
    s[t] = v; __syncthreads();
    for(int off=1; off<128; off<<=1){
        int add = (t>=off) ? s[t-off] : 0;
        __syncthreads(); s[t] += add; __syncthreads();
    }
    bs[t] = (t==0) ? 0 : s[t-1];
}

__global__ void kscanC(const int* __restrict__ cnt, const int* __restrict__ bs,
                       int* __restrict__ offs){
    __shared__ int s[256];
    int t = threadIdx.x;
    int base = blockIdx.x*1024 + t*4;
    int c0=0,c1=0,c2=0,c3=0;
    if(base+0 < N_NODES) c0 = cnt[base+0];
    if(base+1 < N_NODES) c1 = cnt[base+1];
    if(base+2 < N_NODES) c2 = cnt[base+2];
    if(base+3 < N_NODES) c3 = cnt[base+3];
    int v = c0+c1+c2+c3;
    s[t] = v; __syncthreads();
    for(int off=1; off<256; off<<=1){
        int add = (t>=off) ? s[t-off] : 0;
        __syncthreads(); s[t] += add; __syncthreads();
    }
    int ebase = bs[blockIdx.x] + ((t==0) ? 0 : s[t-1]);
    int run = 0;
    run += c0; if(base+0 < N_NODES) offs[base+1] = ebase+run;
    run += c1; if(base+1 < N_NODES) offs[base+2] = ebase+run;
    run += c2; if(base+2 < N_NODES) offs[base+3] = ebase+run;
    run += c3; if(base+3 < N_NODES) offs[base+4] = ebase+run;
    if(blockIdx.x==0 && t==0) offs[0] = 0;
}

__global__ void kscatter(const int* __restrict__ src, const int* __restrict__ dst,
                         int* __restrict__ wp, int* __restrict__ srcp, int* __restrict__ eidp){
    int i = blockIdx.x*256 + threadIdx.x;
    if(i >= N_EDGES) return;
    int d = dst[i];
    int slot = atomicAdd(&wp[d], 1);
    srcp[slot] = src[i];
    eidp[slot] = i;
}

// ---------------- fused 3-inject edge accumulation (one wave per node) ----------------
__global__ void kinject(const int* __restrict__ eidp, const int* __restrict__ offs,
                        const float* __restrict__ ea,
                        const float* __restrict__ w11, const float* __restrict__ b11,
                        const float* __restrict__ w12, const float* __restrict__ b12,
                        const float* __restrict__ w13, const float* __restrict__ b13,
                        float* __restrict__ U1, float* __restrict__ U2,
                        float* __restrict__ U3, float* __restrict__ gsum){
    int gid = blockIdx.x*blockDim.x + threadIdx.x;
    int node = gid >> 6;
    if(node >= N_NODES) return;
    int lane = threadIdx.x & 63;
    int l16  = lane & 15;
    // per-lane weight columns: w1 is [3, nd] row-major
    float wa1=w11[l16],  wb1=w11[16+l16],  wc1=w11[32+l16],  bb1=b11[l16];
    float wa2=w12[lane], wb2=w12[64+lane], wc2=w12[128+lane], bb2=b12[lane];
    float wa3=w13[lane], wb3=w13[64+lane], wc3=w13[128+lane], bb3=b13[lane];
    int beg = offs[node], end = offs[node+1];
    float a1=0.f, a2=0.f, a3=0.f, g=0.f;
    for(int e=beg; e<end; ++e){
        int eid = eidp[e];
        float e0 = ea[eid*3+0], e1 = ea[eid*3+1], e2 = ea[eid*3+2];
        float gate = 1.f/(1.f + expf(-e2));
        a1 += fmaxf(e0*wa1 + e1*wb1 + e2*wc1 + bb1, 0.f)*gate;
        a2 += fmaxf(e0*wa2 + e1*wb2 + e2*wc2 + bb2, 0.f)*gate;
        a3 += fmaxf(e0*wa3 + e1*wb3 + e2*wc3 + bb3, 0.f)*gate;
        g  += gate;
    }
    U2[(size_t)node*64 + lane] = a2;
    U3[(size_t)node*64 + lane] = a3;
    if(lane < 16) U1[node*16 + l16] = a1;
    if(lane == 0) gsum[node] = g;
}

// ---------------- SAGE mean gathers (one wave per node) ----------------
__global__ void kgather16(const float* __restrict__ h, const int* __restrict__ srcp,
                          const int* __restrict__ offs, float* __restrict__ m){
    int gid = blockIdx.x*blockDim.x + threadIdx.x;
    int node = gid >> 6;
    if(node >= N_NODES) return;
    int lane = threadIdx.x & 63;
    int q = lane >> 4, d = lane & 15;
    int beg = offs[node], end = offs[node+1];
    float acc = 0.f;
    for(int e=beg+q; e<end; e+=4) acc += h[(size_t)srcp[e]*16 + d];
    acc += __shfl_down(acc, 32);
    acc += __shfl_down(acc, 16);
    if(lane < 16){
        float c = fmaxf((float)(end-beg), 1.f);
        m[node*16 + lane] = acc / c;
    }
}

__global__ void kgather64(const float* __restrict__ h, const int* __restrict__ srcp,
                          const int* __restrict__ offs, float* __restrict__ m){
    int gid = blockIdx.x*blockDim.x + threadIdx.x;
    int node = gid >> 6;
    if(node >= N_NODES) return;
    int lane = threadIdx.x & 63;
    int beg = offs[node], end = offs[node+1];
    float acc = 0.f;
    int e = beg;
    for(; e+4<=end; e+=4){
        int s0=srcp[e], s1=srcp[e+1], s2=srcp[e+2], s3=srcp[e+3];
        acc += h[(size_t)s0*64 + lane];
        acc += h[(size_t)s1*64 + lane];
        acc += h[(size_t)s2*64 + lane];
        acc += h[(size_t)s3*64 + lane];
    }
    for(; e<end; ++e) acc += h[(size_t)srcp[e]*64 + lane];
    float c = fmaxf((float)(end-beg), 1.f);
    m[(size_t)node*64 + lane] = acc / c;
}

// ---------------- dense per-node kernels ----------------
// h1 = x + U1 @ w2_1 + gs * b2_1            [N,16]
__global__ void kdense0(const float* __restrict__ x, const float* __restrict__ U1,
                        const float* __restrict__ gs, const float* __restrict__ w2,
                        const float* __restrict__ b2, float* __restrict__ h1){
    int idx = blockIdx.x*256 + threadIdx.x;
    if(idx >= N_NODES*16) return;
    int n = idx >> 4, j = idx & 15;
    float acc = x[idx] + gs[n]*b2[j];
    #pragma unroll
    for(int i=0;i<16;i++) acc += U1[n*16+i]*w2[i*16+j];
    h1[idx] = acc;
}

// h2 = relu(bn1(m1@wl + h1@wr + bl)) + U2@w2_2 + gs*b2_2    [N,64]
__global__ void kdense1(const float* __restrict__ m1, const float* __restrict__ h1,
                        const float* __restrict__ U2, const float* __restrict__ gs,
                        const float* __restrict__ wl, const float* __restrict__ bl,
                        const float* __restrict__ wr,
                        const float* __restrict__ w2, const float* __restrict__ b2,
                        const float* __restrict__ bnw, const float* __restrict__ bnb,
                        float* __restrict__ h2){
    int idx = blockIdx.x*256 + threadIdx.x;   // exactly N*64 threads
    int n = idx >> 6, j = idx & 63;
    float a = bl[j];
    #pragma unroll
    for(int i=0;i<16;i++) a += m1[n*16+i]*wl[i*64+j];
    #pragma unroll
    for(int i=0;i<16;i++) a += h1[n*16+i]*wr[i*64+j];
    float t = fmaxf(a*(bnw[j]*BN_RSQRT) + bnb[j], 0.f);
    float b = gs[n]*b2[j];
    #pragma unroll 8
    for(int i=0;i<64;i++) b += U2[(size_t)n*64+i]*w2[i*64+j];
    h2[idx] = t + b;
}

// h3 = relu(bn2(m2@wl + h2@wr + bl)) + U3@w2_3 + gs*b2_3    [N,64]
__global__ void kdense2(const float* __restrict__ m2, const float* __restrict__ h2,
                        const float* __restrict__ U3, const float* __restrict__ gs,
                        const float* __restrict__ wl, const float* __restrict__ bl,
                        const float* __restrict__ wr,
                        const float* __restrict__ w2, const float* __restrict__ b2,
                        const float* __restrict__ bnw, const float* __restrict__ bnb,
                        float* __restrict__ h3){
    int idx = blockIdx.x*256 + threadIdx.x;   // exactly N*64 threads
    int n = idx >> 6, j = idx & 63;
    float a = bl[j];
    #pragma unroll 8
    for(int i=0;i<64;i++) a += m2[(size_t)n*64+i]*wl[i*64+j];
    #pragma unroll 8
    for(int i=0;i<64;i++) a += h2[(size_t)n*64+i]*wr[i*64+j];
    float t = fmaxf(a*(bnw[j]*BN_RSQRT) + bnb[j], 0.f);
    float b = gs[n]*b2[j];
    #pragma unroll 8
    for(int i=0;i<64;i++) b += U3[(size_t)n*64+i]*w2[i*64+j];
    h3[idx] = t + b;
}

// out = relu(bn3(m3@wl + h3@wr + bl))        [N,32]
__global__ void kdense3(const float* __restrict__ m3, const float* __restrict__ h3,
                        const float* __restrict__ wl, const float* __restrict__ bl,
                        const float* __restrict__ wr,
                        const float* __restrict__ bnw, const float* __restrict__ bnb,
                        float* __restrict__ out){
    int idx = blockIdx.x*256 + threadIdx.x;
    if(idx >= N_NODES*32) return;
    int n = idx >> 5, j = idx & 31;
    float a = bl[j];
    #pragma unroll 8
    for(int i=0;i<64;i++) a += m3[(size_t)n*64+i]*wl[i*32+j];
    #pragma unroll 8
    for(int i=0;i<64;i++) a += h3[(size_t)n*64+i]*wr[i*32+j];
    out[idx] = fmaxf(a*(bnw[j]*BN_RSQRT) + bnb[j], 0.f);
}

// ---------------- launch ----------------
extern "C" void kernel_launch(void* const* d_in, const int* in_sizes, int n_in,
                              void* d_out, int out_size, void* d_ws, size_t ws_size,
                              hipStream_t stream){
    const float* x    = (const float*)d_in[0];
    const int*   ei   = (const int*)  d_in[1];
    const float* ea   = (const float*)d_in[2];
    const float* i1w1 = (const float*)d_in[3];
    const float* i1b1 = (const float*)d_in[4];
    const float* i1w2 = (const float*)d_in[5];
    const float* i1b2 = (const float*)d_in[6];
    const float* i2w1 = (const float*)d_in[7];
    const float* i2b1 = (const float*)d_in[8];
    const float* i2w2 = (const float*)d_in[9];
    const float* i2b2 = (const float*)d_in[10];
    const float* i3w1 = (const float*)d_in[11];
    const float* i3b1 = (const float*)d_in[12];
    const float* i3w2 = (const float*)d_in[13];
    const float* i3b2 = (const float*)d_in[14];
    const float* c1wl = (const float*)d_in[15];
    const float* c1bl = (const float*)d_in[16];
    const float* c1wr = (const float*)d_in[17];
    const float* c2wl = (const float*)d_in[18];
    const float* c2bl = (const float*)d_in[19];
    const float* c2wr = (const float*)d_in[20];
    const float* c3wl = (const float*)d_in[21];
    const float* c3bl = (const float*)d_in[22];
    const float* c3wr = (const float*)d_in[23];
    const float* bn1w = (const float*)d_in[24];
    const float* bn1b = (const float*)d_in[25];
    const float* bn2w = (const float*)d_in[26];
    const float* bn2b = (const float*)d_in[27];
    const float* bn3w = (const float*)d_in[28];
    const float* bn3b = (const float*)d_in[29];

    char* ws = (char*)d_ws;
    int*   wp   = (int*)  (ws + o_wp);
    int*   offs = (int*)  (ws + o_off);
    int*   bs   = (int*)  (ws + o_bs);
    int*   srcp = (int*)  (ws + o_srcp);
    int*   eidp = (int*)  (ws + o_eidp);
    float* U1   = (float*)(ws + o_U1);
    float* U2   = (float*)(ws + o_U2);
    float* U3   = (float*)(ws + o_U3);
    float* gs   = (float*)(ws + o_gs);
    float* h1   = (float*)(ws + o_h1);
    float* m1   = (float*)(ws + o_m1);
    float* h2   = (float*)(ws + o_h2);
    float* m2   = (float*)(ws + o_m2);
    float* h3   = (float*)(ws + o_h3);
    float* m3   = (float*)(ws + o_m3);

    const int* src = ei;              // edge_index[0]
    const int* dst = ei + N_EDGES;    // edge_index[1]

    // CSR build
    hipMemsetAsync(wp, 0, (size_t)N_NODES*4, stream);
    khist   <<<N_EDGES/256, 256, 0, stream>>>(dst, wp);
    kscanA  <<<NBLK_SCAN,   256, 0, stream>>>(wp, bs);
    kscanB  <<<1,           128, 0, stream>>>(bs);
    kscanC  <<<NBLK_SCAN,   256, 0, stream>>>(wp, bs, offs);
    hipMemcpyAsync(wp, offs, (size_t)N_NODES*4, hipMemcpyDeviceToDevice, stream);
    kscatter<<<N_EDGES/256, 256, 0, stream>>>(src, dst, wp, srcp, eidp);

    // fused 3x inject edge accumulation
    kinject <<<N_NODES/4, 256, 0, stream>>>(eidp, offs, ea,
                                            i1w1, i1b1, i2w1, i2b1, i3w1, i3b1,
                                            U1, U2, U3, gs);
    // layer 1
    kdense0 <<<N_NODES*16/256, 256, 0, stream>>>(x, U1, gs, i1w2, i1b2, h1);
    kgather16<<<N_NODES/4, 256, 0, stream>>>(h1, srcp, offs, m1);
    kdense1 <<<N_NODES*64/256, 256, 0, stream>>>(m1, h1, U2, gs,
                                                 c1wl, c1bl, c1wr, i2w2, i2b2,
                                                 bn1w, bn1b, h2);
    // layer 2
    kgather64<<<N_NODES/4, 256, 0, stream>>>(h2, srcp, offs, m2);
    kdense2 <<<N_NODES*64/256, 256, 0, stream>>>(m2, h2, U3, gs,
                                                 c2wl, c2bl, c2wr, i3w2, i3b2,
                                                 bn2w, bn2b, h3);
    // layer 3
    kgather64<<<N_NODES/4, 256, 0, stream>>>(h3, srcp, offs, m3);
    kdense3 <<<N_NODES*32/256, 256, 0, stream>>>(m3, h3, c3wl, c3bl, c3wr,
                                                 bn3w, bn3b, (float*)d_out);
}

// Round 2
// 1385.949 us; speedup vs baseline: 1.2143x; 1.2143x over previous
//
#include <hip/hip_runtime.h>
#include <math.h>

#define N_NODES 100000
#define N_EDGES 3200000
#define NBLK_SCAN 98   // ceil(100000/1024)

// ---------------- workspace layout ----------------
constexpr size_t al512(size_t x){ return (x + 511) & ~size_t(511); }
constexpr size_t o_wp   = 0;                                          // int[N]  write-ptrs / histogram
constexpr size_t o_off  = al512(o_wp   + (size_t)N_NODES*4);          // int[N+1] CSR offsets
constexpr size_t o_bs   = al512(o_off  + ((size_t)N_NODES+1)*4);      // int[128] scan block sums
constexpr size_t o_srcp = al512(o_bs   + 128*4);                      // int[E] src permuted by dst
constexpr size_t o_eap  = al512(o_srcp + (size_t)N_EDGES*4);          // float4[E] (e0,e1,e2,gate) permuted; DEAD after kinject
constexpr size_t o_U1   = al512(o_eap  + (size_t)N_EDGES*16);         // f[N*16]
constexpr size_t o_U2   = al512(o_U1   + (size_t)N_NODES*16*4);       // f[N*64]
constexpr size_t o_U3   = al512(o_U2   + (size_t)N_NODES*64*4);       // f[N*64]
constexpr size_t o_gs   = al512(o_U3   + (size_t)N_NODES*64*4);       // f[N] gate sums
constexpr size_t o_h1   = al512(o_gs   + (size_t)N_NODES*4);          // f[N*16]
constexpr size_t o_m1   = al512(o_h1   + (size_t)N_NODES*16*4);       // f[N*16]
// aliases into dead regions:
constexpr size_t o_h2   = o_eap;                                      // f[N*64] (eap dead after kinject)
constexpr size_t o_m2   = o_eap + (size_t)N_NODES*64*4;               // f[N*64] (fits: 51.2MB region)
constexpr size_t o_h3   = o_U2;   // U2 dead after kdense1
constexpr size_t o_m3   = o_m2;   // m2 dead after kdense2

#define BN_RSQRT 0.9999950000374997f   // 1/sqrt(1+1e-5)

// ---------------- CSR build ----------------
__global__ void khist(const int* __restrict__ dst, int* __restrict__ wp){
    int i = blockIdx.x*256 + threadIdx.x;
    if(i < N_EDGES) atomicAdd(&wp[dst[i]], 1);
}

__global__ void kscanA(const int* __restrict__ cnt, int* __restrict__ bs){
    __shared__ int s[256];
    int t = threadIdx.x;
    int base = blockIdx.x*1024 + t*4;
    int v = 0;
    #pragma unroll
    for(int k=0;k<4;k++){ int i = base+k; if(i < N_NODES) v += cnt[i]; }
    s[t] = v; __syncthreads();
    for(int off=128; off>0; off>>=1){ if(t<off) s[t] += s[t+off]; __syncthreads(); }
    if(t==0) bs[blockIdx.x] = s[0];
}

__global__ void kscanB(int* __restrict__ bs){
    __shared__ int s[128];
    int t = threadIdx.x;
    int v = (t < NBLK_SCAN) ? bs[t] : 0;
    s[t] = v; __syncthreads();
    for(int off=1; off<128; off<<=1){
        int add = (t>=off) ? s[t-off] : 0;
        __syncthreads(); s[t] += add; __syncthreads();
    }
    bs[t] = (t==0) ? 0 : s[t-1];
}

__global__ void kscanC(const int* __restrict__ cnt, const int* __restrict__ bs,
                       int* __restrict__ offs){
    __shared__ int s[256];
    int t = threadIdx.x;
    int base = blockIdx.x*1024 + t*4;
    int c0=0,c1=0,c2=0,c3=0;
    if(base+0 < N_NODES) c0 = cnt[base+0];
    if(base+1 < N_NODES) c1 = cnt[base+1];
    if(base+2 < N_NODES) c2 = cnt[base+2];
    if(base+3 < N_NODES) c3 = cnt[base+3];
    int v = c0+c1+c2+c3;
    s[t] = v; __syncthreads();
    for(int off=1; off<256; off<<=1){
        int add = (t>=off) ? s[t-off] : 0;
        __syncthreads(); s[t] += add; __syncthreads();
    }
    int ebase = bs[blockIdx.x] + ((t==0) ? 0 : s[t-1]);
    int run = 0;
    run += c0; if(base+0 < N_NODES) offs[base+1] = ebase+run;
    run += c1; if(base+1 < N_NODES) offs[base+2] = ebase+run;
    run += c2; if(base+2 < N_NODES) offs[base+3] = ebase+run;
    run += c3; if(base+3 < N_NODES) offs[base+4] = ebase+run;
    if(blockIdx.x==0 && t==0) offs[0] = 0;
}

// scatter: permute src AND edge_attr (+precomputed sigmoid gate) into dst-sorted order
__global__ void kscatter(const int* __restrict__ src, const int* __restrict__ dst,
                         const float* __restrict__ ea,
                         int* __restrict__ wp, int* __restrict__ srcp,
                         float4* __restrict__ eap){
    int i = blockIdx.x*256 + threadIdx.x;
    if(i >= N_EDGES) return;
    int d = dst[i];
    float e0 = ea[i*3+0], e1 = ea[i*3+1], e2 = ea[i*3+2];  // coalesced-ish (3 dwords/thread)
    float gate = 1.f/(1.f + expf(-e2));
    int slot = atomicAdd(&wp[d], 1);
    srcp[slot] = src[i];
    eap[slot] = make_float4(e0, e1, e2, gate);
}

// ---------------- fused 3-inject edge accumulation (one wave per node) ----------------
// eap is read SEQUENTIALLY (node's edges are contiguous) -> no random gather.
__global__ void kinject(const float4* __restrict__ eap, const int* __restrict__ offs,
                        const float* __restrict__ w11, const float* __restrict__ b11,
                        const float* __restrict__ w12, const float* __restrict__ b12,
                        const float* __restrict__ w13, const float* __restrict__ b13,
                        float* __restrict__ U1, float* __restrict__ U2,
                        float* __restrict__ U3, float* __restrict__ gsum){
    int gid = blockIdx.x*blockDim.x + threadIdx.x;
    int node = gid >> 6;
    if(node >= N_NODES) return;
    int lane = threadIdx.x & 63;
    int l16  = lane & 15;
    // per-lane weight columns: w1 is [3, nd] row-major
    float wa1=w11[l16],  wb1=w11[16+l16],  wc1=w11[32+l16],  bb1=b11[l16];
    float wa2=w12[lane], wb2=w12[64+lane], wc2=w12[128+lane], bb2=b12[lane];
    float wa3=w13[lane], wb3=w13[64+lane], wc3=w13[128+lane], bb3=b13[lane];
    int beg = offs[node], end = offs[node+1];
    float a1=0.f, a2=0.f, a3=0.f, g=0.f;
    int e = beg;
    for(; e+2<=end; e+=2){
        float4 v0 = eap[e];
        float4 v1 = eap[e+1];
        a1 += fmaxf(fmaf(v0.z,wc1,fmaf(v0.y,wb1,fmaf(v0.x,wa1,bb1))),0.f)*v0.w;
        a2 += fmaxf(fmaf(v0.z,wc2,fmaf(v0.y,wb2,fmaf(v0.x,wa2,bb2))),0.f)*v0.w;
        a3 += fmaxf(fmaf(v0.z,wc3,fmaf(v0.y,wb3,fmaf(v0.x,wa3,bb3))),0.f)*v0.w;
        g  += v0.w;
        a1 += fmaxf(fmaf(v1.z,wc1,fmaf(v1.y,wb1,fmaf(v1.x,wa1,bb1))),0.f)*v1.w;
        a2 += fmaxf(fmaf(v1.z,wc2,fmaf(v1.y,wb2,fmaf(v1.x,wa2,bb2))),0.f)*v1.w;
        a3 += fmaxf(fmaf(v1.z,wc3,fmaf(v1.y,wb3,fmaf(v1.x,wa3,bb3))),0.f)*v1.w;
        g  += v1.w;
    }
    for(; e<end; ++e){
        float4 v = eap[e];
        a1 += fmaxf(fmaf(v.z,wc1,fmaf(v.y,wb1,fmaf(v.x,wa1,bb1))),0.f)*v.w;
        a2 += fmaxf(fmaf(v.z,wc2,fmaf(v.y,wb2,fmaf(v.x,wa2,bb2))),0.f)*v.w;
        a3 += fmaxf(fmaf(v.z,wc3,fmaf(v.y,wb3,fmaf(v.x,wa3,bb3))),0.f)*v.w;
        g  += v.w;
    }
    U2[(size_t)node*64 + lane] = a2;
    U3[(size_t)node*64 + lane] = a3;
    if(lane < 16) U1[node*16 + l16] = a1;
    if(lane == 0) gsum[node] = g;
}

// ---------------- SAGE mean gathers (one wave per node) ----------------
__global__ void kgather16(const float* __restrict__ h, const int* __restrict__ srcp,
                          const int* __restrict__ offs, float* __restrict__ m){
    int gid = blockIdx.x*blockDim.x + threadIdx.x;
    int node = gid >> 6;
    if(node >= N_NODES) return;
    int lane = threadIdx.x & 63;
    int q = lane >> 4, d = lane & 15;
    int beg = offs[node], end = offs[node+1];
    float acc = 0.f;
    for(int e=beg+q; e<end; e+=4) acc += h[(size_t)srcp[e]*16 + d];
    acc += __shfl_down(acc, 32);
    acc += __shfl_down(acc, 16);
    if(lane < 16){
        float c = fmaxf((float)(end-beg), 1.f);
        m[node*16 + lane] = acc / c;
    }
}

__global__ void kgather64(const float* __restrict__ h, const int* __restrict__ srcp,
                          const int* __restrict__ offs, float* __restrict__ m){
    int gid = blockIdx.x*blockDim.x + threadIdx.x;
    int node = gid >> 6;
    if(node >= N_NODES) return;
    int lane = threadIdx.x & 63;
    int beg = offs[node], end = offs[node+1];
    float acc = 0.f;
    int e = beg;
    for(; e+4<=end; e+=4){
        int s0=srcp[e], s1=srcp[e+1], s2=srcp[e+2], s3=srcp[e+3];
        acc += h[(size_t)s0*64 + lane];
        acc += h[(size_t)s1*64 + lane];
        acc += h[(size_t)s2*64 + lane];
        acc += h[(size_t)s3*64 + lane];
    }
    for(; e<end; ++e) acc += h[(size_t)srcp[e]*64 + lane];
    float c = fmaxf((float)(end-beg), 1.f);
    m[(size_t)node*64 + lane] = acc / c;
}

// ---------------- dense per-node kernels ----------------
// h1 = x + U1 @ w2_1 + gs * b2_1            [N,16]
__global__ void kdense0(const float* __restrict__ x, const float* __restrict__ U1,
                        const float* __restrict__ gs, const float* __restrict__ w2,
                        const float* __restrict__ b2, float* __restrict__ h1){
    int idx = blockIdx.x*256 + threadIdx.x;
    if(idx >= N_NODES*16) return;
    int n = idx >> 4, j = idx & 15;
    float acc = x[idx] + gs[n]*b2[j];
    #pragma unroll
    for(int i=0;i<16;i++) acc += U1[n*16+i]*w2[i*16+j];
    h1[idx] = acc;
}

// h2 = relu(bn1(m1@wl + h1@wr + bl)) + U2@w2_2 + gs*b2_2    [N,64]
__global__ void kdense1(const float* __restrict__ m1, const float* __restrict__ h1,
                        const float* __restrict__ U2, const float* __restrict__ gs,
                        const float* __restrict__ wl, const float* __restrict__ bl,
                        const float* __restrict__ wr,
                        const float* __restrict__ w2, const float* __restrict__ b2,
                        const float* __restrict__ bnw, const float* __restrict__ bnb,
                        float* __restrict__ h2){
    int idx = blockIdx.x*256 + threadIdx.x;   // exactly N*64 threads
    int n = idx >> 6, j = idx & 63;
    float a = bl[j];
    #pragma unroll
    for(int i=0;i<16;i++) a += m1[n*16+i]*wl[i*64+j];
    #pragma unroll
    for(int i=0;i<16;i++) a += h1[n*16+i]*wr[i*64+j];
    float t = fmaxf(a*(bnw[j]*BN_RSQRT) + bnb[j], 0.f);
    float b = gs[n]*b2[j];
    #pragma unroll 8
    for(int i=0;i<64;i++) b += U2[(size_t)n*64+i]*w2[i*64+j];
    h2[idx] = t + b;
}

// h3 = relu(bn2(m2@wl + h2@wr + bl)) + U3@w2_3 + gs*b2_3    [N,64]
__global__ void kdense2(const float* __restrict__ m2, const float* __restrict__ h2,
                        const float* __restrict__ U3, const float* __restrict__ gs,
                        const float* __restrict__ wl, const float* __restrict__ bl,
                        const float* __restrict__ wr,
                        const float* __restrict__ w2, const float* __restrict__ b2,
                        const float* __restrict__ bnw, const float* __restrict__ bnb,
                        float* __restrict__ h3){
    int idx = blockIdx.x*256 + threadIdx.x;   // exactly N*64 threads
    int n = idx >> 6, j = idx & 63;
    float a = bl[j];
    #pragma unroll 8
    for(int i=0;i<64;i++) a += m2[(size_t)n*64+i]*wl[i*64+j];
    #pragma unroll 8
    for(int i=0;i<64;i++) a += h2[(size_t)n*64+i]*wr[i*64+j];
    float t = fmaxf(a*(bnw[j]*BN_RSQRT) + bnb[j], 0.f);
    float b = gs[n]*b2[j];
    #pragma unroll 8
    for(int i=0;i<64;i++) b += U3[(size_t)n*64+i]*w2[i*64+j];
    h3[idx] = t + b;
}

// out = relu(bn3(m3@wl + h3@wr + bl))        [N,32]
__global__ void kdense3(const float* __restrict__ m3, const float* __restrict__ h3,
                        const float* __restrict__ wl, const float* __restrict__ bl,
                        const float* __restrict__ wr,
                        const float* __restrict__ bnw, const float* __restrict__ bnb,
                        float* __restrict__ out){
    int idx = blockIdx.x*256 + threadIdx.x;
    if(idx >= N_NODES*32) return;
    int n = idx >> 5, j = idx & 31;
    float a = bl[j];
    #pragma unroll 8
    for(int i=0;i<64;i++) a += m3[(size_t)n*64+i]*wl[i*32+j];
    #pragma unroll 8
    for(int i=0;i<64;i++) a += h3[(size_t)n*64+i]*wr[i*32+j];
    out[idx] = fmaxf(a*(bnw[j]*BN_RSQRT) + bnb[j], 0.f);
}

// ---------------- launch ----------------
extern "C" void kernel_launch(void* const* d_in, const int* in_sizes, int n_in,
                              void* d_out, int out_size, void* d_ws, size_t ws_size,
                              hipStream_t stream){
    const float* x    = (const float*)d_in[0];
    const int*   ei   = (const int*)  d_in[1];
    const float* ea   = (const float*)d_in[2];
    const float* i1w1 = (const float*)d_in[3];
    const float* i1b1 = (const float*)d_in[4];
    const float* i1w2 = (const float*)d_in[5];
    const float* i1b2 = (const float*)d_in[6];
    const float* i2w1 = (const float*)d_in[7];
    const float* i2b1 = (const float*)d_in[8];
    const float* i2w2 = (const float*)d_in[9];
    const float* i2b2 = (const float*)d_in[10];
    const float* i3w1 = (const float*)d_in[11];
    const float* i3b1 = (const float*)d_in[12];
    const float* i3w2 = (const float*)d_in[13];
    const float* i3b2 = (const float*)d_in[14];
    const float* c1wl = (const float*)d_in[15];
    const float* c1bl = (const float*)d_in[16];
    const float* c1wr = (const float*)d_in[17];
    const float* c2wl = (const float*)d_in[18];
    const float* c2bl = (const float*)d_in[19];
    const float* c2wr = (const float*)d_in[20];
    const float* c3wl = (const float*)d_in[21];
    const float* c3bl = (const float*)d_in[22];
    const float* c3wr = (const float*)d_in[23];
    const float* bn1w = (const float*)d_in[24];
    const float* bn1b = (const float*)d_in[25];
    const float* bn2w = (const float*)d_in[26];
    const float* bn2b = (const float*)d_in[27];
    const float* bn3w = (const float*)d_in[28];
    const float* bn3b = (const float*)d_in[29];

    char* ws = (char*)d_ws;
    int*    wp   = (int*)   (ws + o_wp);
    int*    offs = (int*)   (ws + o_off);
    int*    bs   = (int*)   (ws + o_bs);
    int*    srcp = (int*)   (ws + o_srcp);
    float4* eap  = (float4*)(ws + o_eap);
    float*  U1   = (float*) (ws + o_U1);
    float*  U2   = (float*) (ws + o_U2);
    float*  U3   = (float*) (ws + o_U3);
    float*  gs   = (float*) (ws + o_gs);
    float*  h1   = (float*) (ws + o_h1);
    float*  m1   = (float*) (ws + o_m1);
    float*  h2   = (float*) (ws + o_h2);
    float*  m2   = (float*) (ws + o_m2);
    float*  h3   = (float*) (ws + o_h3);
    float*  m3   = (float*) (ws + o_m3);

    const int* src = ei;              // edge_index[0]
    const int* dst = ei + N_EDGES;    // edge_index[1]

    // CSR build (+ permute edge_attr with fused sigmoid into eap)
    hipMemsetAsync(wp, 0, (size_t)N_NODES*4, stream);
    khist   <<<N_EDGES/256, 256, 0, stream>>>(dst, wp);
    kscanA  <<<NBLK_SCAN,   256, 0, stream>>>(wp, bs);
    kscanB  <<<1,           128, 0, stream>>>(bs);
    kscanC  <<<NBLK_SCAN,   256, 0, stream>>>(wp, bs, offs);
    hipMemcpyAsync(wp, offs, (size_t)N_NODES*4, hipMemcpyDeviceToDevice, stream);
    kscatter<<<N_EDGES/256, 256, 0, stream>>>(src, dst, ea, wp, srcp, eap);

    // fused 3x inject edge accumulation (sequential eap reads)
    kinject <<<N_NODES/4, 256, 0, stream>>>(eap, offs,
                                            i1w1, i1b1, i2w1, i2b1, i3w1, i3b1,
                                            U1, U2, U3, gs);
    // layer 1
    kdense0 <<<N_NODES*16/256, 256, 0, stream>>>(x, U1, gs, i1w2, i1b2, h1);
    kgather16<<<N_NODES/4, 256, 0, stream>>>(h1, srcp, offs, m1);
    kdense1 <<<N_NODES*64/256, 256, 0, stream>>>(m1, h1, U2, gs,
                                                 c1wl, c1bl, c1wr, i2w2, i2b2,
                                                 bn1w, bn1b, h2);
    // layer 2
    kgather64<<<N_NODES/4, 256, 0, stream>>>(h2, srcp, offs, m2);
    kdense2 <<<N_NODES*64/256, 256, 0, stream>>>(m2, h2, U3, gs,
                                                 c2wl, c2bl, c2wr, i3w2, i3b2,
                                                 bn2w, bn2b, h3);
    // layer 3
    kgather64<<<N_NODES/4, 256, 0, stream>>>(h3, srcp, offs, m3);
    kdense3 <<<N_NODES*32/256, 256, 0, stream>>>(m3, h3, c3wl, c3bl, c3wr,
                                                 bn3w, bn3b, (float*)d_out);
}

// Round 3
// 1045.204 us; speedup vs baseline: 1.6101x; 1.3260x over previous
//
#include <hip/hip_runtime.h>
#include <math.h>

#define N_NODES 100000
#define N_EDGES 3200000
#define NBLK_SCAN 98   // ceil(100000/1024)

// ---------------- workspace layout ----------------
constexpr size_t al512(size_t x){ return (x + 511) & ~size_t(511); }
constexpr size_t o_wp   = 0;                                          // int[N]  write-ptrs / histogram
constexpr size_t o_off  = al512(o_wp   + (size_t)N_NODES*4);          // int[N+1] CSR offsets
constexpr size_t o_bs   = al512(o_off  + ((size_t)N_NODES+1)*4);      // int[128] scan block sums
constexpr size_t o_srcp = al512(o_bs   + 128*4);                      // int[E] src permuted by dst
constexpr size_t o_eap  = al512(o_srcp + (size_t)N_EDGES*4);          // float4[E] (e0,e1,e2,gate) permuted; DEAD after kinject
constexpr size_t o_U1   = al512(o_eap  + (size_t)N_EDGES*16);         // f[N*16]
constexpr size_t o_U2   = al512(o_U1   + (size_t)N_NODES*16*4);       // f[N*64]
constexpr size_t o_U3   = al512(o_U2   + (size_t)N_NODES*64*4);       // f[N*64]
constexpr size_t o_gs   = al512(o_U3   + (size_t)N_NODES*64*4);       // f[N] gate sums
constexpr size_t o_h1   = al512(o_gs   + (size_t)N_NODES*4);          // f[N*16]
constexpr size_t o_m1   = al512(o_h1   + (size_t)N_NODES*16*4);       // f[N*16]
// aliases into dead regions:
constexpr size_t o_h2   = o_eap;                                      // f[N*64] (eap dead after kinject)
constexpr size_t o_m2   = o_eap + (size_t)N_NODES*64*4;               // f[N*64]
constexpr size_t o_h3   = o_U2;   // U2 dead after kdense1
constexpr size_t o_m3   = o_m2;   // m2 dead after kdense2

#define BN_RSQRT 0.9999950000374997f   // 1/sqrt(1+1e-5)

__device__ __forceinline__ float4 ld4(const float* p){ return *(const float4*)p; }
__device__ __forceinline__ float fc(const float4& v, int i){ return ((const float*)&v)[i]; }

// ---------------- CSR build ----------------
__global__ void khist(const int* __restrict__ dst, int* __restrict__ wp){
    int i = blockIdx.x*256 + threadIdx.x;
    if(i < N_EDGES) atomicAdd(&wp[dst[i]], 1);
}

__global__ void kscanA(const int* __restrict__ cnt, int* __restrict__ bs){
    __shared__ int s[256];
    int t = threadIdx.x;
    int base = blockIdx.x*1024 + t*4;
    int v = 0;
    #pragma unroll
    for(int k=0;k<4;k++){ int i = base+k; if(i < N_NODES) v += cnt[i]; }
    s[t] = v; __syncthreads();
    for(int off=128; off>0; off>>=1){ if(t<off) s[t] += s[t+off]; __syncthreads(); }
    if(t==0) bs[blockIdx.x] = s[0];
}

__global__ void kscanB(int* __restrict__ bs){
    __shared__ int s[128];
    int t = threadIdx.x;
    int v = (t < NBLK_SCAN) ? bs[t] : 0;
    s[t] = v; __syncthreads();
    for(int off=1; off<128; off<<=1){
        int add = (t>=off) ? s[t-off] : 0;
        __syncthreads(); s[t] += add; __syncthreads();
    }
    bs[t] = (t==0) ? 0 : s[t-1];
}

__global__ void kscanC(const int* __restrict__ cnt, const int* __restrict__ bs,
                       int* __restrict__ offs){
    __shared__ int s[256];
    int t = threadIdx.x;
    int base = blockIdx.x*1024 + t*4;
    int c0=0,c1=0,c2=0,c3=0;
    if(base+0 < N_NODES) c0 = cnt[base+0];
    if(base+1 < N_NODES) c1 = cnt[base+1];
    if(base+2 < N_NODES) c2 = cnt[base+2];
    if(base+3 < N_NODES) c3 = cnt[base+3];
    int v = c0+c1+c2+c3;
    s[t] = v; __syncthreads();
    for(int off=1; off<256; off<<=1){
        int add = (t>=off) ? s[t-off] : 0;
        __syncthreads(); s[t] += add; __syncthreads();
    }
    int ebase = bs[blockIdx.x] + ((t==0) ? 0 : s[t-1]);
    int run = 0;
    run += c0; if(base+0 < N_NODES) offs[base+1] = ebase+run;
    run += c1; if(base+1 < N_NODES) offs[base+2] = ebase+run;
    run += c2; if(base+2 < N_NODES) offs[base+3] = ebase+run;
    run += c3; if(base+3 < N_NODES) offs[base+4] = ebase+run;
    if(blockIdx.x==0 && t==0) offs[0] = 0;
}

// scatter: permute src AND edge_attr (+precomputed sigmoid gate) into dst-sorted order
__global__ void kscatter(const int* __restrict__ src, const int* __restrict__ dst,
                         const float* __restrict__ ea,
                         int* __restrict__ wp, int* __restrict__ srcp,
                         float4* __restrict__ eap){
    int i = blockIdx.x*256 + threadIdx.x;
    if(i >= N_EDGES) return;
    int d = dst[i];
    float e0 = ea[i*3+0], e1 = ea[i*3+1], e2 = ea[i*3+2];
    float gate = 1.f/(1.f + expf(-e2));
    int slot = atomicAdd(&wp[d], 1);
    srcp[slot] = src[i];
    eap[slot] = make_float4(e0, e1, e2, gate);
}

// ---------------- fused 3-inject edge accumulation (one wave per node) ----------------
__global__ void kinject(const float4* __restrict__ eap, const int* __restrict__ offs,
                        const float* __restrict__ w11, const float* __restrict__ b11,
                        const float* __restrict__ w12, const float* __restrict__ b12,
                        const float* __restrict__ w13, const float* __restrict__ b13,
                        float* __restrict__ U1, float* __restrict__ U2,
                        float* __restrict__ U3, float* __restrict__ gsum){
    int gid = blockIdx.x*blockDim.x + threadIdx.x;
    int node = gid >> 6;
    if(node >= N_NODES) return;
    int lane = threadIdx.x & 63;
    int l16  = lane & 15;
    float wa1=w11[l16],  wb1=w11[16+l16],  wc1=w11[32+l16],  bb1=b11[l16];
    float wa2=w12[lane], wb2=w12[64+lane], wc2=w12[128+lane], bb2=b12[lane];
    float wa3=w13[lane], wb3=w13[64+lane], wc3=w13[128+lane], bb3=b13[lane];
    int beg = offs[node], end = offs[node+1];
    float a1=0.f, a2=0.f, a3=0.f, g=0.f;
    int e = beg;
    for(; e+2<=end; e+=2){
        float4 v0 = eap[e];
        float4 v1 = eap[e+1];
        a1 += fmaxf(fmaf(v0.z,wc1,fmaf(v0.y,wb1,fmaf(v0.x,wa1,bb1))),0.f)*v0.w;
        a2 += fmaxf(fmaf(v0.z,wc2,fmaf(v0.y,wb2,fmaf(v0.x,wa2,bb2))),0.f)*v0.w;
        a3 += fmaxf(fmaf(v0.z,wc3,fmaf(v0.y,wb3,fmaf(v0.x,wa3,bb3))),0.f)*v0.w;
        g  += v0.w;
        a1 += fmaxf(fmaf(v1.z,wc1,fmaf(v1.y,wb1,fmaf(v1.x,wa1,bb1))),0.f)*v1.w;
        a2 += fmaxf(fmaf(v1.z,wc2,fmaf(v1.y,wb2,fmaf(v1.x,wa2,bb2))),0.f)*v1.w;
        a3 += fmaxf(fmaf(v1.z,wc3,fmaf(v1.y,wb3,fmaf(v1.x,wa3,bb3))),0.f)*v1.w;
        g  += v1.w;
    }
    for(; e<end; ++e){
        float4 v = eap[e];
        a1 += fmaxf(fmaf(v.z,wc1,fmaf(v.y,wb1,fmaf(v.x,wa1,bb1))),0.f)*v.w;
        a2 += fmaxf(fmaf(v.z,wc2,fmaf(v.y,wb2,fmaf(v.x,wa2,bb2))),0.f)*v.w;
        a3 += fmaxf(fmaf(v.z,wc3,fmaf(v.y,wb3,fmaf(v.x,wa3,bb3))),0.f)*v.w;
        g  += v.w;
    }
    U2[(size_t)node*64 + lane] = a2;
    U3[(size_t)node*64 + lane] = a3;
    if(lane < 16) U1[node*16 + l16] = a1;
    if(lane == 0) gsum[node] = g;
}

// ---------------- SAGE mean gathers (one wave per node) ----------------
__global__ void kgather16(const float* __restrict__ h, const int* __restrict__ srcp,
                          const int* __restrict__ offs, float* __restrict__ m){
    int gid = blockIdx.x*blockDim.x + threadIdx.x;
    int node = gid >> 6;
    if(node >= N_NODES) return;
    int lane = threadIdx.x & 63;
    int q = lane >> 4, d = lane & 15;
    int beg = offs[node], end = offs[node+1];
    float acc = 0.f;
    for(int e=beg+q; e<end; e+=4) acc += h[(size_t)srcp[e]*16 + d];
    acc += __shfl_down(acc, 32);
    acc += __shfl_down(acc, 16);
    if(lane < 16){
        float c = fmaxf((float)(end-beg), 1.f);
        m[node*16 + lane] = acc / c;
    }
}

__global__ void kgather64(const float* __restrict__ h, const int* __restrict__ srcp,
                          const int* __restrict__ offs, float* __restrict__ m){
    int gid = blockIdx.x*blockDim.x + threadIdx.x;
    int node = gid >> 6;
    if(node >= N_NODES) return;
    int lane = threadIdx.x & 63;
    int beg = offs[node], end = offs[node+1];
    float acc = 0.f;
    int e = beg;
    for(; e+4<=end; e+=4){
        int s0=srcp[e], s1=srcp[e+1], s2=srcp[e+2], s3=srcp[e+3];
        acc += h[(size_t)s0*64 + lane];
        acc += h[(size_t)s1*64 + lane];
        acc += h[(size_t)s2*64 + lane];
        acc += h[(size_t)s3*64 + lane];
    }
    for(; e<end; ++e) acc += h[(size_t)srcp[e]*64 + lane];
    float c = fmaxf((float)(end-beg), 1.f);
    m[(size_t)node*64 + lane] = acc / c;
}

// ---------------- dense per-node kernels (LDS weights + 4x4 register tiles) ----------------

// h1 = x + U1 @ w2_1 + gs * b2_1            [N,16]
__global__ __launch_bounds__(256) void kdense0(const float* __restrict__ x, const float* __restrict__ U1,
                        const float* __restrict__ gs, const float* __restrict__ w2,
                        const float* __restrict__ b2, float* __restrict__ h1){
    __shared__ float sw[256];
    int t = threadIdx.x;
    sw[t] = w2[t];
    __syncthreads();
    int idx = blockIdx.x*256 + t;            // grid is exactly N*16/256
    int n = idx >> 4, j = idx & 15;
    float acc = x[idx] + gs[n]*b2[j];
    const float4* row = (const float4*)(U1 + n*16);
    #pragma unroll
    for(int i4=0;i4<4;i4++){
        float4 r = row[i4];
        acc += r.x*sw[(i4*4+0)*16 + j];
        acc += r.y*sw[(i4*4+1)*16 + j];
        acc += r.z*sw[(i4*4+2)*16 + j];
        acc += r.w*sw[(i4*4+3)*16 + j];
    }
    h1[idx] = acc;
}

// h2 = relu(bn1(m1@wl + h1@wr + bl)) + U2@w2_2 + gs*b2_2    [N,64]
// block: 256 thr = 4 waves x (16 jg x 4 ng); 64 nodes/block, 4n x 4j per thread
__global__ __launch_bounds__(256) void kdense1(const float* __restrict__ m1, const float* __restrict__ h1,
                        const float* __restrict__ U2, const float* __restrict__ gs,
                        const float* __restrict__ wl, const float* __restrict__ bl,
                        const float* __restrict__ wr,
                        const float* __restrict__ w2, const float* __restrict__ b2,
                        const float* __restrict__ bnw, const float* __restrict__ bnb,
                        float* __restrict__ h2){
    __shared__ float4 swl[16*16];   // 16x64
    __shared__ float4 swr[16*16];   // 16x64
    __shared__ float4 sw2[64*16];   // 64x64
    int t = threadIdx.x;
    swl[t] = ((const float4*)wl)[t];
    swr[t] = ((const float4*)wr)[t];
    #pragma unroll
    for(int k=0;k<4;k++) sw2[t + 256*k] = ((const float4*)w2)[t + 256*k];
    __syncthreads();

    int w = t>>6, l = t&63;
    int jg = l&15, j0 = jg*4, ng = l>>4;
    int nb = blockIdx.x*64 + w*16 + ng*4;
    int nn[4];
    #pragma unroll
    for(int k=0;k<4;k++) nn[k] = (nb+k < N_NODES) ? nb+k : N_NODES-1;

    float a[4][4], b[4][4];
    float4 blv = ld4(bl + j0);
    float4 b2v = ld4(b2 + j0);
    #pragma unroll
    for(int k=0;k<4;k++){
        float g = gs[nn[k]];
        a[k][0]=blv.x; a[k][1]=blv.y; a[k][2]=blv.z; a[k][3]=blv.w;
        b[k][0]=g*b2v.x; b[k][1]=g*b2v.y; b[k][2]=g*b2v.z; b[k][3]=g*b2v.w;
    }
    // phase A: 16-dim dots (m1@wl + h1@wr)
    #pragma unroll
    for(int i=0;i<16;i+=4){
        float4 rm[4], rh[4];
        #pragma unroll
        for(int k=0;k<4;k++){ rm[k] = ld4(m1 + nn[k]*16 + i); rh[k] = ld4(h1 + nn[k]*16 + i); }
        #pragma unroll
        for(int ii=0;ii<4;ii++){
            float4 wL = swl[(i+ii)*16 + jg];
            float4 wR = swr[(i+ii)*16 + jg];
            #pragma unroll
            for(int k=0;k<4;k++){
                float vm = fc(rm[k],ii), vh = fc(rh[k],ii);
                a[k][0] = fmaf(vm,wL.x, fmaf(vh,wR.x, a[k][0]));
                a[k][1] = fmaf(vm,wL.y, fmaf(vh,wR.y, a[k][1]));
                a[k][2] = fmaf(vm,wL.z, fmaf(vh,wR.z, a[k][2]));
                a[k][3] = fmaf(vm,wL.w, fmaf(vh,wR.w, a[k][3]));
            }
        }
    }
    // phase B: 64-dim dot (U2@w2)
    #pragma unroll 4
    for(int i=0;i<64;i+=4){
        float4 ru[4];
        #pragma unroll
        for(int k=0;k<4;k++) ru[k] = ld4(U2 + (size_t)nn[k]*64 + i);
        #pragma unroll
        for(int ii=0;ii<4;ii++){
            float4 wv = sw2[(i+ii)*16 + jg];
            #pragma unroll
            for(int k=0;k<4;k++){
                float vu = fc(ru[k],ii);
                b[k][0] = fmaf(vu,wv.x,b[k][0]);
                b[k][1] = fmaf(vu,wv.y,b[k][1]);
                b[k][2] = fmaf(vu,wv.z,b[k][2]);
                b[k][3] = fmaf(vu,wv.w,b[k][3]);
            }
        }
    }
    float4 bw = ld4(bnw + j0), bb = ld4(bnb + j0);
    #pragma unroll
    for(int k=0;k<4;k++){
        if(nb+k < N_NODES){
            float4 o;
            o.x = fmaxf(a[k][0]*(bw.x*BN_RSQRT)+bb.x,0.f) + b[k][0];
            o.y = fmaxf(a[k][1]*(bw.y*BN_RSQRT)+bb.y,0.f) + b[k][1];
            o.z = fmaxf(a[k][2]*(bw.z*BN_RSQRT)+bb.z,0.f) + b[k][2];
            o.w = fmaxf(a[k][3]*(bw.w*BN_RSQRT)+bb.w,0.f) + b[k][3];
            *(float4*)(h2 + (size_t)(nb+k)*64 + j0) = o;
        }
    }
}

// h3 = relu(bn2(m2@wl + h2@wr + bl)) + U3@w2_3 + gs*b2_3    [N,64]
__global__ __launch_bounds__(256) void kdense2(const float* __restrict__ m2, const float* __restrict__ h2,
                        const float* __restrict__ U3, const float* __restrict__ gs,
                        const float* __restrict__ wl, const float* __restrict__ bl,
                        const float* __restrict__ wr,
                        const float* __restrict__ w2, const float* __restrict__ b2,
                        const float* __restrict__ bnw, const float* __restrict__ bnb,
                        float* __restrict__ h3){
    __shared__ float4 swl[64*16];   // 64x64
    __shared__ float4 swr[64*16];
    __shared__ float4 sw2[64*16];
    int t = threadIdx.x;
    #pragma unroll
    for(int k=0;k<4;k++){
        swl[t + 256*k] = ((const float4*)wl)[t + 256*k];
        swr[t + 256*k] = ((const float4*)wr)[t + 256*k];
        sw2[t + 256*k] = ((const float4*)w2)[t + 256*k];
    }
    __syncthreads();

    int w = t>>6, l = t&63;
    int jg = l&15, j0 = jg*4, ng = l>>4;
    int nb = blockIdx.x*64 + w*16 + ng*4;
    int nn[4];
    #pragma unroll
    for(int k=0;k<4;k++) nn[k] = (nb+k < N_NODES) ? nb+k : N_NODES-1;

    float a[4][4], b[4][4];
    float4 blv = ld4(bl + j0);
    float4 b2v = ld4(b2 + j0);
    #pragma unroll
    for(int k=0;k<4;k++){
        float g = gs[nn[k]];
        a[k][0]=blv.x; a[k][1]=blv.y; a[k][2]=blv.z; a[k][3]=blv.w;
        b[k][0]=g*b2v.x; b[k][1]=g*b2v.y; b[k][2]=g*b2v.z; b[k][3]=g*b2v.w;
    }
    // phase A: m2@wl + h2@wr (64-dim)
    #pragma unroll 4
    for(int i=0;i<64;i+=4){
        float4 rm[4], rh[4];
        #pragma unroll
        for(int k=0;k<4;k++){ rm[k] = ld4(m2 + (size_t)nn[k]*64 + i); rh[k] = ld4(h2 + (size_t)nn[k]*64 + i); }
        #pragma unroll
        for(int ii=0;ii<4;ii++){
            float4 wL = swl[(i+ii)*16 + jg];
            float4 wR = swr[(i+ii)*16 + jg];
            #pragma unroll
            for(int k=0;k<4;k++){
                float vm = fc(rm[k],ii), vh = fc(rh[k],ii);
                a[k][0] = fmaf(vm,wL.x, fmaf(vh,wR.x, a[k][0]));
                a[k][1] = fmaf(vm,wL.y, fmaf(vh,wR.y, a[k][1]));
                a[k][2] = fmaf(vm,wL.z, fmaf(vh,wR.z, a[k][2]));
                a[k][3] = fmaf(vm,wL.w, fmaf(vh,wR.w, a[k][3]));
            }
        }
    }
    // phase B: U3@w2 (64-dim)
    #pragma unroll 4
    for(int i=0;i<64;i+=4){
        float4 ru[4];
        #pragma unroll
        for(int k=0;k<4;k++) ru[k] = ld4(U3 + (size_t)nn[k]*64 + i);
        #pragma unroll
        for(int ii=0;ii<4;ii++){
            float4 wv = sw2[(i+ii)*16 + jg];
            #pragma unroll
            for(int k=0;k<4;k++){
                float vu = fc(ru[k],ii);
                b[k][0] = fmaf(vu,wv.x,b[k][0]);
                b[k][1] = fmaf(vu,wv.y,b[k][1]);
                b[k][2] = fmaf(vu,wv.z,b[k][2]);
                b[k][3] = fmaf(vu,wv.w,b[k][3]);
            }
        }
    }
    float4 bw = ld4(bnw + j0), bb = ld4(bnb + j0);
    #pragma unroll
    for(int k=0;k<4;k++){
        if(nb+k < N_NODES){
            float4 o;
            o.x = fmaxf(a[k][0]*(bw.x*BN_RSQRT)+bb.x,0.f) + b[k][0];
            o.y = fmaxf(a[k][1]*(bw.y*BN_RSQRT)+bb.y,0.f) + b[k][1];
            o.z = fmaxf(a[k][2]*(bw.z*BN_RSQRT)+bb.z,0.f) + b[k][2];
            o.w = fmaxf(a[k][3]*(bw.w*BN_RSQRT)+bb.w,0.f) + b[k][3];
            *(float4*)(h3 + (size_t)(nb+k)*64 + j0) = o;
        }
    }
}

// out = relu(bn3(m3@wl + h3@wr + bl))        [N,32]
// block: 256 thr = 4 waves x (8 jg x 8 ng); 128 nodes/block
__global__ __launch_bounds__(256) void kdense3(const float* __restrict__ m3, const float* __restrict__ h3,
                        const float* __restrict__ wl, const float* __restrict__ bl,
                        const float* __restrict__ wr,
                        const float* __restrict__ bnw, const float* __restrict__ bnb,
                        float* __restrict__ out){
    __shared__ float4 swl[64*8];    // 64x32
    __shared__ float4 swr[64*8];
    int t = threadIdx.x;
    #pragma unroll
    for(int k=0;k<2;k++){
        swl[t + 256*k] = ((const float4*)wl)[t + 256*k];
        swr[t + 256*k] = ((const float4*)wr)[t + 256*k];
    }
    __syncthreads();

    int w = t>>6, l = t&63;
    int jg = l&7, j0 = jg*4, ng = l>>3;
    int nb = blockIdx.x*128 + w*32 + ng*4;
    int nn[4];
    #pragma unroll
    for(int k=0;k<4;k++) nn[k] = (nb+k < N_NODES) ? nb+k : N_NODES-1;

    float a[4][4];
    float4 blv = ld4(bl + j0);
    #pragma unroll
    for(int k=0;k<4;k++){ a[k][0]=blv.x; a[k][1]=blv.y; a[k][2]=blv.z; a[k][3]=blv.w; }
    #pragma unroll 4
    for(int i=0;i<64;i+=4){
        float4 rm[4], rh[4];
        #pragma unroll
        for(int k=0;k<4;k++){ rm[k] = ld4(m3 + (size_t)nn[k]*64 + i); rh[k] = ld4(h3 + (size_t)nn[k]*64 + i); }
        #pragma unroll
        for(int ii=0;ii<4;ii++){
            float4 wL = swl[(i+ii)*8 + jg];
            float4 wR = swr[(i+ii)*8 + jg];
            #pragma unroll
            for(int k=0;k<4;k++){
                float vm = fc(rm[k],ii), vh = fc(rh[k],ii);
                a[k][0] = fmaf(vm,wL.x, fmaf(vh,wR.x, a[k][0]));
                a[k][1] = fmaf(vm,wL.y, fmaf(vh,wR.y, a[k][1]));
                a[k][2] = fmaf(vm,wL.z, fmaf(vh,wR.z, a[k][2]));
                a[k][3] = fmaf(vm,wL.w, fmaf(vh,wR.w, a[k][3]));
            }
        }
    }
    float4 bw = ld4(bnw + j0), bb = ld4(bnb + j0);
    #pragma unroll
    for(int k=0;k<4;k++){
        if(nb+k < N_NODES){
            float4 o;
            o.x = fmaxf(a[k][0]*(bw.x*BN_RSQRT)+bb.x,0.f);
            o.y = fmaxf(a[k][1]*(bw.y*BN_RSQRT)+bb.y,0.f);
            o.z = fmaxf(a[k][2]*(bw.z*BN_RSQRT)+bb.z,0.f);
            o.w = fmaxf(a[k][3]*(bw.w*BN_RSQRT)+bb.w,0.f);
            *(float4*)(out + (size_t)(nb+k)*32 + j0) = o;
        }
    }
}

// ---------------- launch ----------------
extern "C" void kernel_launch(void* const* d_in, const int* in_sizes, int n_in,
                              void* d_out, int out_size, void* d_ws, size_t ws_size,
                              hipStream_t stream){
    const float* x    = (const float*)d_in[0];
    const int*   ei   = (const int*)  d_in[1];
    const float* ea   = (const float*)d_in[2];
    const float* i1w1 = (const float*)d_in[3];
    const float* i1b1 = (const float*)d_in[4];
    const float* i1w2 = (const float*)d_in[5];
    const float* i1b2 = (const float*)d_in[6];
    const float* i2w1 = (const float*)d_in[7];
    const float* i2b1 = (const float*)d_in[8];
    const float* i2w2 = (const float*)d_in[9];
    const float* i2b2 = (const float*)d_in[10];
    const float* i3w1 = (const float*)d_in[11];
    const float* i3b1 = (const float*)d_in[12];
    const float* i3w2 = (const float*)d_in[13];
    const float* i3b2 = (const float*)d_in[14];
    const float* c1wl = (const float*)d_in[15];
    const float* c1bl = (const float*)d_in[16];
    const float* c1wr = (const float*)d_in[17];
    const float* c2wl = (const float*)d_in[18];
    const float* c2bl = (const float*)d_in[19];
    const float* c2wr = (const float*)d_in[20];
    const float* c3wl = (const float*)d_in[21];
    const float* c3bl = (const float*)d_in[22];
    const float* c3wr = (const float*)d_in[23];
    const float* bn1w = (const float*)d_in[24];
    const float* bn1b = (const float*)d_in[25];
    const float* bn2w = (const float*)d_in[26];
    const float* bn2b = (const float*)d_in[27];
    const float* bn3w = (const float*)d_in[28];
    const float* bn3b = (const float*)d_in[29];

    char* ws = (char*)d_ws;
    int*    wp   = (int*)   (ws + o_wp);
    int*    offs = (int*)   (ws + o_off);
    int*    bs   = (int*)   (ws + o_bs);
    int*    srcp = (int*)   (ws + o_srcp);
    float4* eap  = (float4*)(ws + o_eap);
    float*  U1   = (float*) (ws + o_U1);
    float*  U2   = (float*) (ws + o_U2);
    float*  U3   = (float*) (ws + o_U3);
    float*  gs   = (float*) (ws + o_gs);
    float*  h1   = (float*) (ws + o_h1);
    float*  m1   = (float*) (ws + o_m1);
    float*  h2   = (float*) (ws + o_h2);
    float*  m2   = (float*) (ws + o_m2);
    float*  h3   = (float*) (ws + o_h3);
    float*  m3   = (float*) (ws + o_m3);

    const int* src = ei;              // edge_index[0]
    const int* dst = ei + N_EDGES;    // edge_index[1]

    // CSR build (+ permute edge_attr with fused sigmoid into eap)
    hipMemsetAsync(wp, 0, (size_t)N_NODES*4, stream);
    khist   <<<N_EDGES/256, 256, 0, stream>>>(dst, wp);
    kscanA  <<<NBLK_SCAN,   256, 0, stream>>>(wp, bs);
    kscanB  <<<1,           128, 0, stream>>>(bs);
    kscanC  <<<NBLK_SCAN,   256, 0, stream>>>(wp, bs, offs);
    hipMemcpyAsync(wp, offs, (size_t)N_NODES*4, hipMemcpyDeviceToDevice, stream);
    kscatter<<<N_EDGES/256, 256, 0, stream>>>(src, dst, ea, wp, srcp, eap);

    // fused 3x inject edge accumulation (sequential eap reads)
    kinject <<<N_NODES/4, 256, 0, stream>>>(eap, offs,
                                            i1w1, i1b1, i2w1, i2b1, i3w1, i3b1,
                                            U1, U2, U3, gs);
    // layer 1
    kdense0 <<<N_NODES*16/256, 256, 0, stream>>>(x, U1, gs, i1w2, i1b2, h1);
    kgather16<<<N_NODES/4, 256, 0, stream>>>(h1, srcp, offs, m1);
    kdense1 <<<(N_NODES+63)/64, 256, 0, stream>>>(m1, h1, U2, gs,
                                                 c1wl, c1bl, c1wr, i2w2, i2b2,
                                                 bn1w, bn1b, h2);
    // layer 2
    kgather64<<<N_NODES/4, 256, 0, stream>>>(h2, srcp, offs, m2);
    kdense2 <<<(N_NODES+63)/64, 256, 0, stream>>>(m2, h2, U3, gs,
                                                 c2wl, c2bl, c2wr, i3w2, i3b2,
                                                 bn2w, bn2b, h3);
    // layer 3
    kgather64<<<N_NODES/4, 256, 0, stream>>>(h3, srcp, offs, m3);
    kdense3 <<<(N_NODES+127)/128, 256, 0, stream>>>(m3, h3, c3wl, c3bl, c3wr,
                                                 bn3w, bn3b, (float*)d_out);
}